// Round 17
// baseline (457.550 us; speedup 1.0000x reference)
//
#include <hip/hip_runtime.h>

#define Bn 32
#define Tn 24
#define Dn 32
#define Hn 32
#define Cn 1024
#define DC (Dn*Cn)      /* 32768 */
#define TDC (Tn*Dn*Cn)  /* 786432 */
#define PPXN 1024       /* unpadded 32x32 plane */
#define IMGS (PPXN*32)  /* shorts per image: 4 planes * 1024 * 8 */
#define SCALE 1.442695041f

typedef __attribute__((ext_vector_type(8))) short bf16x8;
typedef __attribute__((ext_vector_type(4))) float f32x4;

__device__ __forceinline__ unsigned cvt_pk(float lo, float hi) {
    unsigned r; asm("v_cvt_pk_bf16_f32 %0, %1, %2" : "=v"(r) : "v"(lo), "v"(hi)); return r;
}
__device__ __forceinline__ float lo16f(unsigned u) { return __builtin_bit_cast(float, u << 16); }
__device__ __forceinline__ float hi16f(unsigned u) { return __builtin_bit_cast(float, u & 0xffff0000u); }
__device__ __forceinline__ float rcp_(float x) { return __builtin_amdgcn_rcpf(x); }
__device__ __forceinline__ float exp2_(float x) { return __builtin_amdgcn_exp2f(x); }
__device__ __forceinline__ bf16x8 bc(int4 v) { return __builtin_bit_cast(bf16x8, v); }

// LDS-only barrier: no vmcnt drain (x-prefetch loads & sp stores stay in flight).
__device__ __forceinline__ void lds_barrier() {
    asm volatile("s_waitcnt lgkmcnt(0)\n\ts_barrier" ::: "memory");
}

struct __align__(16) LdsT {
    unsigned short Xh[2][4][16][48];  // [buf][cell][b][d pad48] bf16(x) hi
    float Hf[2][4][16][36];           // [buf][cell][b][hid pad36] fp32 h
};  // 30720 B -> 2 blocks/CU

// ---- LSTM: grid 512 = 256 cellgroups(4 cells) x 2 bslices; 512 thr = 8 waves.
// wave w: cell ci = w>>1, gate-half gh = w&1 (M=16, N=64, W=64 u32 -> no spill).
// x loaded as ONE dense float4/thread/step (16B = 4 consecutive cells).
__global__ __launch_bounds__(512, 2)
void lstm_k17(const float* __restrict__ x,
              const float* __restrict__ Wih,
              const float* __restrict__ Whh,
              const float* __restrict__ bih,
              const float* __restrict__ bhh,
              unsigned short* __restrict__ sp)
{
    __shared__ LdsT lds;
    const int tid  = threadIdx.x;
    const int lane = tid & 63;
    const int wave = tid >> 6;
    const int ci   = wave >> 1;
    const int gh   = wave & 1;
    const int l16  = lane & 15;
    const int kg   = lane >> 4;
    const int bid  = blockIdx.x;
    const int xcd  = bid & 7, v = bid >> 3;        // v 0..63
    const int cg   = xcd * 32 + (v & 31);           // 0..255, XCD-contiguous groups
    const int bs   = v >> 5;                        // 0..1
    const int cellbase = cg * 4;
    const int cell = cellbase + ci;
    const int gb0  = bs * 16;

    // ---- W fragments (int4), split hi/lo via cvt_pk, pre-scaled by log2e ----
    int4 wihh[4], wihl[4], whhh[4], whhl[4];
    float biasr[4];
#pragma unroll
    for (int q = 0; q < 4; ++q) {
        const int g = q * 32 + gh * 16 + l16;
        const float* wp = Wih + (size_t)cell * 4096 + g * 32 + kg * 8;
        const float* hp = Whh + (size_t)cell * 4096 + g * 32 + kg * 8;
        float wv[8], hv[8];
#pragma unroll
        for (int j = 0; j < 8; ++j) { wv[j] = wp[j] * SCALE; hv[j] = hp[j] * SCALE; }
        unsigned a0 = cvt_pk(wv[0], wv[1]), a1 = cvt_pk(wv[2], wv[3]);
        unsigned a2 = cvt_pk(wv[4], wv[5]), a3 = cvt_pk(wv[6], wv[7]);
        wihh[q] = int4{(int)a0, (int)a1, (int)a2, (int)a3};
        wihl[q] = int4{(int)cvt_pk(wv[0] - lo16f(a0), wv[1] - hi16f(a0)),
                       (int)cvt_pk(wv[2] - lo16f(a1), wv[3] - hi16f(a1)),
                       (int)cvt_pk(wv[4] - lo16f(a2), wv[5] - hi16f(a2)),
                       (int)cvt_pk(wv[6] - lo16f(a3), wv[7] - hi16f(a3))};
        unsigned b0 = cvt_pk(hv[0], hv[1]), b1 = cvt_pk(hv[2], hv[3]);
        unsigned b2 = cvt_pk(hv[4], hv[5]), b3 = cvt_pk(hv[6], hv[7]);
        whhh[q] = int4{(int)b0, (int)b1, (int)b2, (int)b3};
        whhl[q] = int4{(int)cvt_pk(hv[0] - lo16f(b0), hv[1] - hi16f(b0)),
                       (int)cvt_pk(hv[2] - lo16f(b1), hv[3] - hi16f(b1)),
                       (int)cvt_pk(hv[4] - lo16f(b2), hv[5] - hi16f(b2)),
                       (int)cvt_pk(hv[6] - lo16f(b3), hv[7] - hi16f(b3))};
        biasr[q] = (bih[cell * 128 + g] + bhh[cell * 128 + g]) * SCALE;
    }

    // ---- x staging: thread -> (b = tid>>5, d = tid&31); float4 = 4 cells ----
    const int sb = tid >> 5;
    const int sd = tid & 31;
    const float* xg0 = x + (size_t)(gb0 + sb) * TDC + (size_t)sd * Cn + cellbase;
    const float* xcur = xg0 + DC;

    // ---- sp store map (gh==0 waves): lane -> (b_loc = lane&15, kg2 = lane>>4);
    //      unpadded plane: pixel index == cell ----
    const int b_loc = lane & 15, kg2 = lane >> 4;
    unsigned short* spcur = sp + (((size_t)(gb0 + b_loc) * (Tn * 4) + kg2) * PPXN + cell) * 8;

    float hD[4] = {}, cst[4] = {};
    float4 gx = *(const float4*)xg0;

    for (int t = 0; t < Tn; ++t) {
        const int bufi = t & 1;
        // -- stage x(t): 4 cells bf16-hi, 4 b16 stores --
        {
            unsigned u01 = cvt_pk(gx.x, gx.y), u23 = cvt_pk(gx.z, gx.w);
            lds.Xh[bufi][0][sb][sd] = (unsigned short)u01;
            lds.Xh[bufi][1][sb][sd] = (unsigned short)(u01 >> 16);
            lds.Xh[bufi][2][sb][sd] = (unsigned short)u23;
            lds.Xh[bufi][3][sb][sd] = (unsigned short)(u23 >> 16);
        }
        // -- write h(t-1) -> Hf[bufi] (rows kg*4+r, col gh*16+l16) --
#pragma unroll
        for (int r = 0; r < 4; ++r)
            lds.Hf[bufi][ci][kg * 4 + r][gh * 16 + l16] = hD[r];
        // -- prefetch x(t+1): one dense float4; stays in flight across barrier --
        if (t < Tn - 1) {
            gx = *(const float4*)xcur;
            xcur += DC;
        }
        lds_barrier();

        // -- fragments (rows b = l16, k = kg*8..+7) --
        int4 xfh = *(const int4*)&lds.Xh[bufi][ci][l16][kg * 8];
        const float* hp = &lds.Hf[bufi][ci][l16][kg * 8];
        float4 ha = *(const float4*)hp;
        float4 hb = *(const float4*)(hp + 4);
        unsigned p0 = cvt_pk(ha.x, ha.y), p1 = cvt_pk(ha.z, ha.w);
        unsigned p2 = cvt_pk(hb.x, hb.y), p3 = cvt_pk(hb.z, hb.w);
        int4 hfh = int4{(int)p0, (int)p1, (int)p2, (int)p3};
        int4 hfl = int4{(int)cvt_pk(ha.x - lo16f(p0), ha.y - hi16f(p0)),
                        (int)cvt_pk(ha.z - lo16f(p1), ha.w - hi16f(p1)),
                        (int)cvt_pk(hb.x - lo16f(p2), hb.y - hi16f(p2)),
                        (int)cvt_pk(hb.z - lo16f(p3), hb.w - hi16f(p3))};

        // -- sp store h(t-1) bf16-hi (gh==0 waves; (b_loc,kg2)==(l16,kg) map) --
        if (gh == 0 && t > 0) {
            int4 sv = {(int)p0, (int)p1, (int)p2, (int)p3};
            *(int4*)spcur = sv;
            spcur += IMGS;
        }

        // -- MFMA: 4 q-tiles x 5-term --
        f32x4 acc[4];
#pragma unroll
        for (int q = 0; q < 4; ++q) {
            f32x4 a = {biasr[q], biasr[q], biasr[q], biasr[q]};
            a = __builtin_amdgcn_mfma_f32_16x16x32_bf16(bc(xfh), bc(wihh[q]), a, 0, 0, 0);
            a = __builtin_amdgcn_mfma_f32_16x16x32_bf16(bc(xfh), bc(wihl[q]), a, 0, 0, 0);
            a = __builtin_amdgcn_mfma_f32_16x16x32_bf16(bc(hfh), bc(whhh[q]), a, 0, 0, 0);
            a = __builtin_amdgcn_mfma_f32_16x16x32_bf16(bc(hfl), bc(whhh[q]), a, 0, 0, 0);
            a = __builtin_amdgcn_mfma_f32_16x16x32_bf16(bc(hfh), bc(whhl[q]), a, 0, 0, 0);
            acc[q] = a;
        }

        // -- gates (pre-scaled by log2e): rows b = kg*4+r, h col gh*16+l16 --
#pragma unroll
        for (int r = 0; r < 4; ++r) {
            float gi = acc[0][r], gf = acc[1][r];
            float gg = acc[2][r], go = acc[3][r];
            float ig = rcp_(1.f + exp2_(-gi));
            float fg = rcp_(1.f + exp2_(-gf));
            float gt = 1.f - 2.f * rcp_(1.f + exp2_(gg + gg));
            float og = rcp_(1.f + exp2_(-go));
            float c  = fg * cst[r] + ig * gt;
            cst[r] = c;
            float tc = 1.f - 2.f * rcp_(1.f + exp2_((2.f * SCALE) * c));
            hD[r] = og * tc;
        }
    }

    // ---- epilogue: flush h(Tn-1) ----
#pragma unroll
    for (int r = 0; r < 4; ++r)
        lds.Hf[0][ci][kg * 4 + r][gh * 16 + l16] = hD[r];
    lds_barrier();
    if (gh == 0) {
        const float* hq = &lds.Hf[0][ci][l16][kg * 8];
        float4 ea = *(const float4*)hq;
        float4 eb = *(const float4*)(hq + 4);
        int4 sv = {(int)cvt_pk(ea.x, ea.y), (int)cvt_pk(ea.z, ea.w),
                   (int)cvt_pk(eb.x, eb.y), (int)cvt_pk(eb.z, eb.w)};
        *(int4*)spcur = sv;
    }
}

// ---- conv: 768 blocks (b,t) x 512 thr, 2 px/thread, predicated boundary,
//      fp32 math, fused sigmoid. No halo, no zero_halo kernel. ----
__global__ __launch_bounds__(512, 4)
void conv_k17(const unsigned short* __restrict__ sp,
              const float* __restrict__ cw,
              const float* __restrict__ cb,
              float* __restrict__ out)
{
    __shared__ float wlds[9][32];
    const int tid = threadIdx.x;
    const int img = blockIdx.x;
    if (tid < 288) wlds[tid >> 5][tid & 31] = cw[(tid & 31) * 9 + (tid >> 5)];
    __syncthreads();
    const float bias = cb[0];
    float acc[2] = {bias, bias};
    int pxv[2], mv[2], nv[2];
#pragma unroll
    for (int pk = 0; pk < 2; ++pk) {
        int px = tid + pk * 512;
        pxv[pk] = px; mv[pk] = px >> 5; nv[pk] = px & 31;
    }
#pragma unroll
    for (int hc = 0; hc < 4; ++hc) {
        float4 wa[9], wb[9];
#pragma unroll
        for (int tap = 0; tap < 9; ++tap) {
            wa[tap] = *(const float4*)&wlds[tap][hc * 8];
            wb[tap] = *(const float4*)&wlds[tap][hc * 8 + 4];
        }
        const unsigned short* plane = sp + (size_t)(img * 4 + hc) * (PPXN * 8);
#pragma unroll
        for (int pk = 0; pk < 2; ++pk) {
            const unsigned short* base = plane + (size_t)pxv[pk] * 8;
            float a = acc[pk];
#pragma unroll
            for (int dm = -1; dm <= 1; ++dm)
#pragma unroll
                for (int dn = -1; dn <= 1; ++dn) {
                    const int tap = (dm + 1) * 3 + (dn + 1);
                    const bool ok = ((unsigned)(mv[pk] + dm) < 32u) &&
                                    ((unsigned)(nv[pk] + dn) < 32u);
                    int4 v = {0, 0, 0, 0};
                    if (ok) v = *(const int4*)(base + (dm * 32 + dn) * 8);
                    float4 w0 = wa[tap], w1 = wb[tap];
                    a = fmaf(lo16f((unsigned)v.x), w0.x, a);
                    a = fmaf(hi16f((unsigned)v.x), w0.y, a);
                    a = fmaf(lo16f((unsigned)v.y), w0.z, a);
                    a = fmaf(hi16f((unsigned)v.y), w0.w, a);
                    a = fmaf(lo16f((unsigned)v.z), w1.x, a);
                    a = fmaf(hi16f((unsigned)v.z), w1.y, a);
                    a = fmaf(lo16f((unsigned)v.w), w1.z, a);
                    a = fmaf(hi16f((unsigned)v.w), w1.w, a);
                }
            acc[pk] = a;
        }
    }
#pragma unroll
    for (int pk = 0; pk < 2; ++pk)
        out[(size_t)img * 1024 + pxv[pk]] = rcp_(1.f + exp2_(-SCALE * acc[pk]));
}

extern "C" void kernel_launch(void* const* d_in, const int* in_sizes, int n_in,
                              void* d_out, int out_size, void* d_ws, size_t ws_size,
                              hipStream_t stream) {
    const float* x   = (const float*)d_in[0];
    const float* Wih = (const float*)d_in[1];
    const float* Whh = (const float*)d_in[2];
    const float* bih = (const float*)d_in[3];
    const float* bhh = (const float*)d_in[4];
    const float* cw  = (const float*)d_in[5];
    const float* cb  = (const float*)d_in[6];
    float* out = (float*)d_out;
    unsigned short* sp = (unsigned short*)d_ws;  // bf16 (B,T, chunk4, 32,32, 8ch), 49.2 MB

    lstm_k17<<<512, 512, 0, stream>>>(x, Wih, Whh, bih, bhh, sp);
    conv_k17<<<Bn * Tn, 512, 0, stream>>>(sp, cw, cb, out);
}

// Round 18
// 95.259 us; speedup vs baseline: 4.8032x; 4.8032x over previous
//
#include <hip/hip_runtime.h>

#define Bn 32
#define Tn 24
#define Dn 32
#define Hn 32
#define Cn 1024
#define DC (Dn*Cn)      /* 32768 */
#define TDC (Tn*Dn*Cn)  /* 786432 */
#define PPXN 1024       /* unpadded 32x32 plane */
#define IMGS (PPXN*32)  /* shorts per image: 4 planes * 1024 * 8 */
#define SCALE 1.442695041f

typedef __attribute__((ext_vector_type(8))) short bf16x8;
typedef __attribute__((ext_vector_type(4))) float f32x4;

__device__ __forceinline__ unsigned cvt_pk(float lo, float hi) {
    unsigned r; asm("v_cvt_pk_bf16_f32 %0, %1, %2" : "=v"(r) : "v"(lo), "v"(hi)); return r;
}
__device__ __forceinline__ float lo16f(unsigned u) { return __builtin_bit_cast(float, u << 16); }
__device__ __forceinline__ float hi16f(unsigned u) { return __builtin_bit_cast(float, u & 0xffff0000u); }
__device__ __forceinline__ float rcp_(float x) { return __builtin_amdgcn_rcpf(x); }
__device__ __forceinline__ float exp2_(float x) { return __builtin_amdgcn_exp2f(x); }
__device__ __forceinline__ bf16x8 bc(int4 v) { return __builtin_bit_cast(bf16x8, v); }

// LDS-only barrier: no vmcnt drain (global loads stay in flight).
__device__ __forceinline__ void lds_barrier() {
    asm volatile("s_waitcnt lgkmcnt(0)\n\ts_barrier" ::: "memory");
}

struct __align__(16) LdsT {
    unsigned short Xh[2][4][16][48];  // [buf][cell][b][d pad48] bf16(x) hi
    float Hf[2][4][16][36];           // [buf][cell][b][hid pad36] fp32 h
};  // 30720 B -> 2 blocks/CU

// ---- LSTM: grid 512 = 256 cellgroups(4 cells) x 2 bslices; 512 thr = 8 waves.
// wave w: cell ci = w>>1, gate-half gh = w&1 (M=16, N=64, W=64 u32 -> no spill).
// x loaded as ONE dense float4/thread/step (16B = 4 consecutive cells).
__global__ __launch_bounds__(512, 2)
void lstm_k18(const float* __restrict__ x,
              const float* __restrict__ Wih,
              const float* __restrict__ Whh,
              const float* __restrict__ bih,
              const float* __restrict__ bhh,
              unsigned short* __restrict__ sp)
{
    __shared__ LdsT lds;
    const int tid  = threadIdx.x;
    const int lane = tid & 63;
    const int wave = tid >> 6;
    const int ci   = wave >> 1;
    const int gh   = wave & 1;
    const int l16  = lane & 15;
    const int kg   = lane >> 4;
    const int bid  = blockIdx.x;
    const int xcd  = bid & 7, v = bid >> 3;        // v 0..63
    const int cg   = xcd * 32 + (v & 31);           // 0..255, XCD-contiguous groups
    const int bs   = v >> 5;                        // 0..1
    const int cellbase = cg * 4;
    const int cell = cellbase + ci;
    const int gb0  = bs * 16;

    // ---- W fragments (int4), split hi/lo via cvt_pk, pre-scaled by log2e ----
    int4 wihh[4], wihl[4], whhh[4], whhl[4];
    float biasr[4];
#pragma unroll
    for (int q = 0; q < 4; ++q) {
        const int g = q * 32 + gh * 16 + l16;
        const float* wp = Wih + (size_t)cell * 4096 + g * 32 + kg * 8;
        const float* hp = Whh + (size_t)cell * 4096 + g * 32 + kg * 8;
        float wv[8], hv[8];
#pragma unroll
        for (int j = 0; j < 8; ++j) { wv[j] = wp[j] * SCALE; hv[j] = hp[j] * SCALE; }
        unsigned a0 = cvt_pk(wv[0], wv[1]), a1 = cvt_pk(wv[2], wv[3]);
        unsigned a2 = cvt_pk(wv[4], wv[5]), a3 = cvt_pk(wv[6], wv[7]);
        wihh[q] = int4{(int)a0, (int)a1, (int)a2, (int)a3};
        wihl[q] = int4{(int)cvt_pk(wv[0] - lo16f(a0), wv[1] - hi16f(a0)),
                       (int)cvt_pk(wv[2] - lo16f(a1), wv[3] - hi16f(a1)),
                       (int)cvt_pk(wv[4] - lo16f(a2), wv[5] - hi16f(a2)),
                       (int)cvt_pk(wv[6] - lo16f(a3), wv[7] - hi16f(a3))};
        unsigned b0 = cvt_pk(hv[0], hv[1]), b1 = cvt_pk(hv[2], hv[3]);
        unsigned b2 = cvt_pk(hv[4], hv[5]), b3 = cvt_pk(hv[6], hv[7]);
        whhh[q] = int4{(int)b0, (int)b1, (int)b2, (int)b3};
        whhl[q] = int4{(int)cvt_pk(hv[0] - lo16f(b0), hv[1] - hi16f(b0)),
                       (int)cvt_pk(hv[2] - lo16f(b1), hv[3] - hi16f(b1)),
                       (int)cvt_pk(hv[4] - lo16f(b2), hv[5] - hi16f(b2)),
                       (int)cvt_pk(hv[6] - lo16f(b3), hv[7] - hi16f(b3))};
        biasr[q] = (bih[cell * 128 + g] + bhh[cell * 128 + g]) * SCALE;
    }

    // ---- x staging: thread -> (b = tid>>5, d = tid&31); float4 = 4 cells ----
    const int sb = tid >> 5;
    const int sd = tid & 31;
    const float* xg0 = x + (size_t)(gb0 + sb) * TDC + (size_t)sd * Cn + cellbase;
    const float* xcur = xg0 + DC;

    // ---- sp store map (gh==0 waves): lane -> (b_loc = lane&15, kg2 = lane>>4) ----
    const int b_loc = lane & 15, kg2 = lane >> 4;
    unsigned short* spcur = sp + (((size_t)(gb0 + b_loc) * (Tn * 4) + kg2) * PPXN + cell) * 8;

    float hD[4] = {}, cst[4] = {};
    float4 gx = *(const float4*)xg0;

    for (int t = 0; t < Tn; ++t) {
        const int bufi = t & 1;
        // -- stage x(t): 4 cells bf16-hi, 4 b16 stores --
        {
            unsigned u01 = cvt_pk(gx.x, gx.y), u23 = cvt_pk(gx.z, gx.w);
            lds.Xh[bufi][0][sb][sd] = (unsigned short)u01;
            lds.Xh[bufi][1][sb][sd] = (unsigned short)(u01 >> 16);
            lds.Xh[bufi][2][sb][sd] = (unsigned short)u23;
            lds.Xh[bufi][3][sb][sd] = (unsigned short)(u23 >> 16);
        }
        // -- write h(t-1) -> Hf[bufi] (rows kg*4+r, col gh*16+l16) --
#pragma unroll
        for (int r = 0; r < 4; ++r)
            lds.Hf[bufi][ci][kg * 4 + r][gh * 16 + l16] = hD[r];
        // -- prefetch x(t+1): one dense float4; stays in flight across barrier --
        if (t < Tn - 1) {
            gx = *(const float4*)xcur;
            xcur += DC;
        }
        lds_barrier();

        // -- fragments (rows b = l16, k = kg*8..+7) --
        int4 xfh = *(const int4*)&lds.Xh[bufi][ci][l16][kg * 8];
        const float* hp = &lds.Hf[bufi][ci][l16][kg * 8];
        float4 ha = *(const float4*)hp;
        float4 hb = *(const float4*)(hp + 4);
        unsigned p0 = cvt_pk(ha.x, ha.y), p1 = cvt_pk(ha.z, ha.w);
        unsigned p2 = cvt_pk(hb.x, hb.y), p3 = cvt_pk(hb.z, hb.w);
        int4 hfh = int4{(int)p0, (int)p1, (int)p2, (int)p3};
        int4 hfl = int4{(int)cvt_pk(ha.x - lo16f(p0), ha.y - hi16f(p0)),
                        (int)cvt_pk(ha.z - lo16f(p1), ha.w - hi16f(p1)),
                        (int)cvt_pk(hb.x - lo16f(p2), hb.y - hi16f(p2)),
                        (int)cvt_pk(hb.z - lo16f(p3), hb.w - hi16f(p3))};

        // -- sp store h(t-1) bf16-hi (gh==0 waves; (b_loc,kg2)==(l16,kg) map) --
        if (gh == 0 && t > 0) {
            int4 sv = {(int)p0, (int)p1, (int)p2, (int)p3};
            *(int4*)spcur = sv;
            spcur += IMGS;
        }

        // -- MFMA: 4 q-tiles x 5-term --
        f32x4 acc[4];
#pragma unroll
        for (int q = 0; q < 4; ++q) {
            f32x4 a = {biasr[q], biasr[q], biasr[q], biasr[q]};
            a = __builtin_amdgcn_mfma_f32_16x16x32_bf16(bc(xfh), bc(wihh[q]), a, 0, 0, 0);
            a = __builtin_amdgcn_mfma_f32_16x16x32_bf16(bc(xfh), bc(wihl[q]), a, 0, 0, 0);
            a = __builtin_amdgcn_mfma_f32_16x16x32_bf16(bc(hfh), bc(whhh[q]), a, 0, 0, 0);
            a = __builtin_amdgcn_mfma_f32_16x16x32_bf16(bc(hfl), bc(whhh[q]), a, 0, 0, 0);
            a = __builtin_amdgcn_mfma_f32_16x16x32_bf16(bc(hfh), bc(whhl[q]), a, 0, 0, 0);
            acc[q] = a;
        }

        // -- gates (pre-scaled by log2e): rows b = kg*4+r, h col gh*16+l16 --
#pragma unroll
        for (int r = 0; r < 4; ++r) {
            float gi = acc[0][r], gf = acc[1][r];
            float gg = acc[2][r], go = acc[3][r];
            float ig = rcp_(1.f + exp2_(-gi));
            float fg = rcp_(1.f + exp2_(-gf));
            float gt = 1.f - 2.f * rcp_(1.f + exp2_(gg + gg));
            float og = rcp_(1.f + exp2_(-go));
            float c  = fg * cst[r] + ig * gt;
            cst[r] = c;
            float tc = 1.f - 2.f * rcp_(1.f + exp2_((2.f * SCALE) * c));
            hD[r] = og * tc;
        }
    }

    // ---- epilogue: flush h(Tn-1) ----
#pragma unroll
    for (int r = 0; r < 4; ++r)
        lds.Hf[0][ci][kg * 4 + r][gh * 16 + l16] = hD[r];
    lds_barrier();
    if (gh == 0) {
        const float* hq = &lds.Hf[0][ci][l16][kg * 8];
        float4 ea = *(const float4*)hq;
        float4 eb = *(const float4*)(hq + 4);
        int4 sv = {(int)cvt_pk(ea.x, ea.y), (int)cvt_pk(ea.z, ea.w),
                   (int)cvt_pk(eb.x, eb.y), (int)cvt_pk(eb.z, eb.w)};
        *(int4*)spcur = sv;
    }
}

// ---- conv: 768 blocks (b,t) x 512 thr; LDS-staged 34x34x8 bf16 tile with
//      in-LDS zero halo; predication-free inner loop; weights broadcast from LDS.
__global__ __launch_bounds__(512, 4)
void conv_k18(const unsigned short* __restrict__ sp,
              const float* __restrict__ cw,
              const float* __restrict__ cb,
              float* __restrict__ out)
{
    __shared__ unsigned short tile[34 * 34 * 8];   // 18496 shorts = 36992 B
    __shared__ float wlds[9][32];
    const int tid = threadIdx.x;
    const int img = blockIdx.x;
    if (tid < 288) wlds[tid >> 5][tid & 31] = cw[(tid & 31) * 9 + (tid >> 5)];
    // zero the halo ring once (tile halo is never overwritten by interior stores)
    if (tid < 132) {
        int r = tid, m, n;
        if (r < 34)       { m = 0;      n = r; }
        else if (r < 68)  { m = 33;     n = r - 34; }
        else if (r < 100) { m = r - 67; n = 0; }
        else              { m = r - 99; n = 33; }
        *(int4*)&tile[(m * 34 + n) * 8] = int4{0, 0, 0, 0};
    }
    const int m0 = tid >> 5, n0 = tid & 31;
    const float bias = cb[0];
    float acc[2] = {bias, bias};

#pragma unroll
    for (int hc = 0; hc < 4; ++hc) {
        const unsigned short* plane = sp + (size_t)(img * 4 + hc) * (PPXN * 8);
        // issue this chunk's loads before the barrier that ends last chunk's compute
        int4 v0 = *(const int4*)(plane + (size_t)tid * 8);
        int4 v1 = *(const int4*)(plane + (size_t)(tid + 512) * 8);
        if (hc) lds_barrier();            // prior compute reads done before overwrite
        else    lds_barrier();            // halo + weights visible
        *(int4*)&tile[((m0 + 1) * 34 + n0 + 1) * 8] = v0;
        *(int4*)&tile[((m0 + 17) * 34 + n0 + 1) * 8] = v1;
        lds_barrier();

#pragma unroll
        for (int pk = 0; pk < 2; ++pk) {
            const int m = m0 + pk * 16, n = n0;
            float a = acc[pk];
#pragma unroll
            for (int dm = -1; dm <= 1; ++dm)
#pragma unroll
                for (int dn = -1; dn <= 1; ++dn) {
                    const int tap = (dm + 1) * 3 + (dn + 1);
                    int4 v = *(const int4*)&tile[((m + 1 + dm) * 34 + (n + 1 + dn)) * 8];
                    float4 w0 = *(const float4*)&wlds[tap][hc * 8];
                    float4 w1 = *(const float4*)&wlds[tap][hc * 8 + 4];
                    a = fmaf(lo16f((unsigned)v.x), w0.x, a);
                    a = fmaf(hi16f((unsigned)v.x), w0.y, a);
                    a = fmaf(lo16f((unsigned)v.y), w0.z, a);
                    a = fmaf(hi16f((unsigned)v.y), w0.w, a);
                    a = fmaf(lo16f((unsigned)v.z), w1.x, a);
                    a = fmaf(hi16f((unsigned)v.z), w1.y, a);
                    a = fmaf(lo16f((unsigned)v.w), w1.z, a);
                    a = fmaf(hi16f((unsigned)v.w), w1.w, a);
                }
            acc[pk] = a;
        }
    }
#pragma unroll
    for (int pk = 0; pk < 2; ++pk)
        out[(size_t)img * 1024 + tid + pk * 512] = rcp_(1.f + exp2_(-SCALE * acc[pk]));
}

extern "C" void kernel_launch(void* const* d_in, const int* in_sizes, int n_in,
                              void* d_out, int out_size, void* d_ws, size_t ws_size,
                              hipStream_t stream) {
    const float* x   = (const float*)d_in[0];
    const float* Wih = (const float*)d_in[1];
    const float* Whh = (const float*)d_in[2];
    const float* bih = (const float*)d_in[3];
    const float* bhh = (const float*)d_in[4];
    const float* cw  = (const float*)d_in[5];
    const float* cb  = (const float*)d_in[6];
    float* out = (float*)d_out;
    unsigned short* sp = (unsigned short*)d_ws;  // bf16 (B,T, chunk4, 32,32, 8ch), 49.2 MB

    lstm_k18<<<512, 512, 0, stream>>>(x, Wih, Whh, bih, bhh, sp);
    conv_k18<<<Bn * Tn, 512, 0, stream>>>(sp, cw, cb, out);
}

// Round 19
// 84.768 us; speedup vs baseline: 5.3977x; 1.1238x over previous
//
#include <hip/hip_runtime.h>

#define Bn 32
#define Tn 24
#define Dn 32
#define Hn 32
#define Cn 1024
#define DC (Dn*Cn)      /* 32768 */
#define TDC (Tn*Dn*Cn)  /* 786432 */
#define PPXN 1024       /* unpadded 32x32 plane */
#define IMGS (PPXN*32)  /* shorts per image: 4 planes * 1024 * 8 */
#define HSTR 584        /* Hf cell stride (floats): quad store reads hit 4 banks */
#define SCALE 1.442695041f

typedef __attribute__((ext_vector_type(8))) short bf16x8;
typedef __attribute__((ext_vector_type(4))) float f32x4;

__device__ __forceinline__ unsigned cvt_pk(float lo, float hi) {
    unsigned r; asm("v_cvt_pk_bf16_f32 %0, %1, %2" : "=v"(r) : "v"(lo), "v"(hi)); return r;
}
__device__ __forceinline__ float lo16f(unsigned u) { return __builtin_bit_cast(float, u << 16); }
__device__ __forceinline__ float hi16f(unsigned u) { return __builtin_bit_cast(float, u & 0xffff0000u); }
__device__ __forceinline__ float rcp_(float x) { return __builtin_amdgcn_rcpf(x); }
__device__ __forceinline__ float exp2_(float x) { return __builtin_amdgcn_exp2f(x); }
__device__ __forceinline__ bf16x8 bc(int4 v) { return __builtin_bit_cast(bf16x8, v); }

// LDS-only barrier: no vmcnt drain (global loads/stores stay in flight).
__device__ __forceinline__ void lds_barrier() {
    asm volatile("s_waitcnt lgkmcnt(0)\n\ts_barrier" ::: "memory");
}

struct __align__(16) LdsT {
    unsigned short Xh[2][4][16][48];  // [buf][cell][b][d pad48] bf16(x) hi
    float Hf[2][4 * HSTR];            // [buf][cell*HSTR + b*36 + hid] fp32 h
};  // 12288 + 18688 = 30976 B -> 2 blocks/CU

// ---- LSTM: grid 512 = 256 cellgroups(4 cells) x 2 bslices; 512 thr = 8 waves.
// wave w: cell ci = w>>1, gate-half gh = w&1 (M=16, N=64, W=64 u32 -> no spill).
// x loaded as ONE dense float4/thread/step; sp stored as QUAD-DENSE 64-B
// segments (waves 0..3: lane -> cl=lane&3 cell, bq=lane>>2 batch, kg2=wave).
__global__ __launch_bounds__(512, 2)
void lstm_k19(const float* __restrict__ x,
              const float* __restrict__ Wih,
              const float* __restrict__ Whh,
              const float* __restrict__ bih,
              const float* __restrict__ bhh,
              unsigned short* __restrict__ sp)
{
    __shared__ LdsT lds;
    const int tid  = threadIdx.x;
    const int lane = tid & 63;
    const int wave = tid >> 6;
    const int ci   = wave >> 1;
    const int gh   = wave & 1;
    const int l16  = lane & 15;
    const int kg   = lane >> 4;
    const int bid  = blockIdx.x;
    const int xcd  = bid & 7, v = bid >> 3;        // v 0..63
    const int cg   = xcd * 32 + (v & 31);           // 0..255, XCD-contiguous groups
    const int bs   = v >> 5;                        // 0..1
    const int cellbase = cg * 4;
    const int cell = cellbase + ci;
    const int gb0  = bs * 16;

    // ---- W fragments (int4), split hi/lo via cvt_pk, pre-scaled by log2e ----
    int4 wihh[4], wihl[4], whhh[4], whhl[4];
    float biasr[4];
#pragma unroll
    for (int q = 0; q < 4; ++q) {
        const int g = q * 32 + gh * 16 + l16;
        const float* wp = Wih + (size_t)cell * 4096 + g * 32 + kg * 8;
        const float* hp = Whh + (size_t)cell * 4096 + g * 32 + kg * 8;
        float wv[8], hv[8];
#pragma unroll
        for (int j = 0; j < 8; ++j) { wv[j] = wp[j] * SCALE; hv[j] = hp[j] * SCALE; }
        unsigned a0 = cvt_pk(wv[0], wv[1]), a1 = cvt_pk(wv[2], wv[3]);
        unsigned a2 = cvt_pk(wv[4], wv[5]), a3 = cvt_pk(wv[6], wv[7]);
        wihh[q] = int4{(int)a0, (int)a1, (int)a2, (int)a3};
        wihl[q] = int4{(int)cvt_pk(wv[0] - lo16f(a0), wv[1] - hi16f(a0)),
                       (int)cvt_pk(wv[2] - lo16f(a1), wv[3] - hi16f(a1)),
                       (int)cvt_pk(wv[4] - lo16f(a2), wv[5] - hi16f(a2)),
                       (int)cvt_pk(wv[6] - lo16f(a3), wv[7] - hi16f(a3))};
        unsigned b0 = cvt_pk(hv[0], hv[1]), b1 = cvt_pk(hv[2], hv[3]);
        unsigned b2 = cvt_pk(hv[4], hv[5]), b3 = cvt_pk(hv[6], hv[7]);
        whhh[q] = int4{(int)b0, (int)b1, (int)b2, (int)b3};
        whhl[q] = int4{(int)cvt_pk(hv[0] - lo16f(b0), hv[1] - hi16f(b0)),
                       (int)cvt_pk(hv[2] - lo16f(b1), hv[3] - hi16f(b1)),
                       (int)cvt_pk(hv[4] - lo16f(b2), hv[5] - hi16f(b2)),
                       (int)cvt_pk(hv[6] - lo16f(b3), hv[7] - hi16f(b3))};
        biasr[q] = (bih[cell * 128 + g] + bhh[cell * 128 + g]) * SCALE;
    }

    // ---- x staging: thread -> (b = tid>>5, d = tid&31); float4 = 4 cells ----
    const int sb = tid >> 5;
    const int sd = tid & 31;
    const float* xg0 = x + (size_t)(gb0 + sb) * TDC + (size_t)sd * Cn + cellbase;
    const float* xcur = xg0 + DC;

    // ---- sp store map (waves 0..3): lane -> (cl = lane&3, bq = lane>>2), kg2 = wave.
    //      Quad cl=0..3 covers 4 consecutive cells -> 64-B dense segment. ----
    const int cl = lane & 3, bq = lane >> 2;
    unsigned short* spq = sp + ((size_t)(gb0 + bq) * 96 + wave) * (PPXN * 8)
                             + (size_t)(cellbase + cl) * 8;

    float hD[4] = {}, cst[4] = {};
    float4 gx = *(const float4*)xg0;

    for (int t = 0; t < Tn; ++t) {
        const int bufi = t & 1;
        // -- stage x(t): 4 cells bf16-hi, 4 b16 stores --
        {
            unsigned u01 = cvt_pk(gx.x, gx.y), u23 = cvt_pk(gx.z, gx.w);
            lds.Xh[bufi][0][sb][sd] = (unsigned short)u01;
            lds.Xh[bufi][1][sb][sd] = (unsigned short)(u01 >> 16);
            lds.Xh[bufi][2][sb][sd] = (unsigned short)u23;
            lds.Xh[bufi][3][sb][sd] = (unsigned short)(u23 >> 16);
        }
        // -- write h(t-1) -> Hf[bufi] (rows kg*4+r, col gh*16+l16) --
#pragma unroll
        for (int r = 0; r < 4; ++r)
            lds.Hf[bufi][ci * HSTR + (kg * 4 + r) * 36 + gh * 16 + l16] = hD[r];
        // -- prefetch x(t+1): one dense float4; stays in flight across barrier --
        if (t < Tn - 1) {
            gx = *(const float4*)xcur;
            xcur += DC;
        }
        lds_barrier();

        // -- fragments (rows b = l16, k = kg*8..+7) --
        int4 xfh = *(const int4*)&lds.Xh[bufi][ci][l16][kg * 8];
        const float* hp = &lds.Hf[bufi][ci * HSTR + l16 * 36 + kg * 8];
        float4 ha = *(const float4*)hp;
        float4 hb = *(const float4*)(hp + 4);
        unsigned p0 = cvt_pk(ha.x, ha.y), p1 = cvt_pk(ha.z, ha.w);
        unsigned p2 = cvt_pk(hb.x, hb.y), p3 = cvt_pk(hb.z, hb.w);
        int4 hfh = int4{(int)p0, (int)p1, (int)p2, (int)p3};
        int4 hfl = int4{(int)cvt_pk(ha.x - lo16f(p0), ha.y - hi16f(p0)),
                        (int)cvt_pk(ha.z - lo16f(p1), ha.w - hi16f(p1)),
                        (int)cvt_pk(hb.x - lo16f(p2), hb.y - hi16f(p2)),
                        (int)cvt_pk(hb.z - lo16f(p3), hb.w - hi16f(p3))};

        // -- sp store h(t-1): waves 0..3, quad-dense 64-B segments --
        if (wave < 4 && t > 0) {
            const float* hq = &lds.Hf[bufi][cl * HSTR + bq * 36 + wave * 8];
            float4 e0 = *(const float4*)hq;
            float4 e1 = *(const float4*)(hq + 4);
            int4 sv = {(int)cvt_pk(e0.x, e0.y), (int)cvt_pk(e0.z, e0.w),
                       (int)cvt_pk(e1.x, e1.y), (int)cvt_pk(e1.z, e1.w)};
            *(int4*)(spq + (size_t)(t - 1) * (4 * PPXN * 8)) = sv;
        }

        // -- MFMA: 4 q-tiles x 5-term --
        f32x4 acc[4];
#pragma unroll
        for (int q = 0; q < 4; ++q) {
            f32x4 a = {biasr[q], biasr[q], biasr[q], biasr[q]};
            a = __builtin_amdgcn_mfma_f32_16x16x32_bf16(bc(xfh), bc(wihh[q]), a, 0, 0, 0);
            a = __builtin_amdgcn_mfma_f32_16x16x32_bf16(bc(xfh), bc(wihl[q]), a, 0, 0, 0);
            a = __builtin_amdgcn_mfma_f32_16x16x32_bf16(bc(hfh), bc(whhh[q]), a, 0, 0, 0);
            a = __builtin_amdgcn_mfma_f32_16x16x32_bf16(bc(hfl), bc(whhh[q]), a, 0, 0, 0);
            a = __builtin_amdgcn_mfma_f32_16x16x32_bf16(bc(hfh), bc(whhl[q]), a, 0, 0, 0);
            acc[q] = a;
        }

        // -- gates (pre-scaled by log2e): rows b = kg*4+r, h col gh*16+l16 --
#pragma unroll
        for (int r = 0; r < 4; ++r) {
            float gi = acc[0][r], gf = acc[1][r];
            float gg = acc[2][r], go = acc[3][r];
            float ig = rcp_(1.f + exp2_(-gi));
            float fg = rcp_(1.f + exp2_(-gf));
            float gt = 1.f - 2.f * rcp_(1.f + exp2_(gg + gg));
            float og = rcp_(1.f + exp2_(-go));
            float c  = fg * cst[r] + ig * gt;
            cst[r] = c;
            float tc = 1.f - 2.f * rcp_(1.f + exp2_((2.f * SCALE) * c));
            hD[r] = og * tc;
        }
    }

    // ---- epilogue: flush h(Tn-1) ----
#pragma unroll
    for (int r = 0; r < 4; ++r)
        lds.Hf[0][ci * HSTR + (kg * 4 + r) * 36 + gh * 16 + l16] = hD[r];
    lds_barrier();
    if (wave < 4) {
        const float* hq = &lds.Hf[0][cl * HSTR + bq * 36 + wave * 8];
        float4 e0 = *(const float4*)hq;
        float4 e1 = *(const float4*)(hq + 4);
        int4 sv = {(int)cvt_pk(e0.x, e0.y), (int)cvt_pk(e0.z, e0.w),
                   (int)cvt_pk(e1.x, e1.y), (int)cvt_pk(e1.z, e1.w)};
        *(int4*)(spq + (size_t)(Tn - 1) * (4 * PPXN * 8)) = sv;
    }
}

// ---- conv: 768 blocks (b,t) x 512 thr; LDS-staged 34x34x8 bf16 tile with
//      in-LDS zero halo; predication-free inner loop; weights broadcast from LDS.
__global__ __launch_bounds__(512, 4)
void conv_k18(const unsigned short* __restrict__ sp,
              const float* __restrict__ cw,
              const float* __restrict__ cb,
              float* __restrict__ out)
{
    __shared__ unsigned short tile[34 * 34 * 8];   // 36992 B
    __shared__ float wlds[9][32];
    const int tid = threadIdx.x;
    const int img = blockIdx.x;
    if (tid < 288) wlds[tid >> 5][tid & 31] = cw[(tid & 31) * 9 + (tid >> 5)];
    if (tid < 132) {
        int r = tid, m, n;
        if (r < 34)       { m = 0;      n = r; }
        else if (r < 68)  { m = 33;     n = r - 34; }
        else if (r < 100) { m = r - 67; n = 0; }
        else              { m = r - 99; n = 33; }
        *(int4*)&tile[(m * 34 + n) * 8] = int4{0, 0, 0, 0};
    }
    const int m0 = tid >> 5, n0 = tid & 31;
    const float bias = cb[0];
    float acc[2] = {bias, bias};

#pragma unroll
    for (int hc = 0; hc < 4; ++hc) {
        const unsigned short* plane = sp + (size_t)(img * 4 + hc) * (PPXN * 8);
        int4 v0 = *(const int4*)(plane + (size_t)tid * 8);
        int4 v1 = *(const int4*)(plane + (size_t)(tid + 512) * 8);
        lds_barrier();                    // prior compute done / halo visible
        *(int4*)&tile[((m0 + 1) * 34 + n0 + 1) * 8] = v0;
        *(int4*)&tile[((m0 + 17) * 34 + n0 + 1) * 8] = v1;
        lds_barrier();

#pragma unroll
        for (int pk = 0; pk < 2; ++pk) {
            const int m = m0 + pk * 16, n = n0;
            float a = acc[pk];
#pragma unroll
            for (int dm = -1; dm <= 1; ++dm)
#pragma unroll
                for (int dn = -1; dn <= 1; ++dn) {
                    const int tap = (dm + 1) * 3 + (dn + 1);
                    int4 v = *(const int4*)&tile[((m + 1 + dm) * 34 + (n + 1 + dn)) * 8];
                    float4 w0 = *(const float4*)&wlds[tap][hc * 8];
                    float4 w1 = *(const float4*)&wlds[tap][hc * 8 + 4];
                    a = fmaf(lo16f((unsigned)v.x), w0.x, a);
                    a = fmaf(hi16f((unsigned)v.x), w0.y, a);
                    a = fmaf(lo16f((unsigned)v.y), w0.z, a);
                    a = fmaf(hi16f((unsigned)v.y), w0.w, a);
                    a = fmaf(lo16f((unsigned)v.z), w1.x, a);
                    a = fmaf(hi16f((unsigned)v.z), w1.y, a);
                    a = fmaf(lo16f((unsigned)v.w), w1.z, a);
                    a = fmaf(hi16f((unsigned)v.w), w1.w, a);
                }
            acc[pk] = a;
        }
    }
#pragma unroll
    for (int pk = 0; pk < 2; ++pk)
        out[(size_t)img * 1024 + tid + pk * 512] = rcp_(1.f + exp2_(-SCALE * acc[pk]));
}

extern "C" void kernel_launch(void* const* d_in, const int* in_sizes, int n_in,
                              void* d_out, int out_size, void* d_ws, size_t ws_size,
                              hipStream_t stream) {
    const float* x   = (const float*)d_in[0];
    const float* Wih = (const float*)d_in[1];
    const float* Whh = (const float*)d_in[2];
    const float* bih = (const float*)d_in[3];
    const float* bhh = (const float*)d_in[4];
    const float* cw  = (const float*)d_in[5];
    const float* cb  = (const float*)d_in[6];
    float* out = (float*)d_out;
    unsigned short* sp = (unsigned short*)d_ws;  // bf16 (B,T, chunk4, 32,32, 8ch), 49.2 MB

    lstm_k19<<<512, 512, 0, stream>>>(x, Wih, Whh, bih, bhh, sp);
    conv_k18<<<Bn * Tn, 512, 0, stream>>>(sp, cw, cb, out);
}

// Round 20
// 83.542 us; speedup vs baseline: 5.4769x; 1.0147x over previous
//
#include <hip/hip_runtime.h>

#define Bn 32
#define Tn 24
#define Dn 32
#define Hn 32
#define Cn 1024
#define DC (Dn*Cn)      /* 32768 */
#define TDC (Tn*Dn*Cn)  /* 786432 */
#define PPXN 1024       /* unpadded 32x32 plane */
#define IMGS (PPXN*32)  /* shorts per image: 4 planes * 1024 * 8 */
#define HSTR 584        /* Hf cell stride (floats) */
#define SCALE 1.442695041f

typedef __attribute__((ext_vector_type(8))) short bf16x8;
typedef __attribute__((ext_vector_type(4))) float f32x4;

__device__ __forceinline__ unsigned cvt_pk(float lo, float hi) {
    unsigned r; asm("v_cvt_pk_bf16_f32 %0, %1, %2" : "=v"(r) : "v"(lo), "v"(hi)); return r;
}
__device__ __forceinline__ float lo16f(unsigned u) { return __builtin_bit_cast(float, u << 16); }
__device__ __forceinline__ float hi16f(unsigned u) { return __builtin_bit_cast(float, u & 0xffff0000u); }
__device__ __forceinline__ float rcp_(float x) { return __builtin_amdgcn_rcpf(x); }
__device__ __forceinline__ float exp2_(float x) { return __builtin_amdgcn_exp2f(x); }
__device__ __forceinline__ bf16x8 bc(int4 v) { return __builtin_bit_cast(bf16x8, v); }

// LDS-only barrier: no vmcnt drain (global loads/stores stay in flight).
__device__ __forceinline__ void lds_barrier() {
    asm volatile("s_waitcnt lgkmcnt(0)\n\ts_barrier" ::: "memory");
}

struct __align__(16) LdsT {
    unsigned short Xh[2][4][16][48];  // [buf][cell][b][d pad48] bf16(x) hi
    float Hf[2][4 * HSTR];            // [buf][cell*HSTR + b*36 + hid] fp32 h
};  // 30976 B -> 2 blocks/CU

// ---- LSTM: grid 512 = 256 cellgroups(4 cells) x 2 bslices; 512 thr = 8 waves.
// wave w: cell ci = w>>1, gate-half gh = w&1. x: one dense float4/thread/step.
// sp: quad-dense 64-B stores (waves 0..3). t-loop unrolled x2: bufi is a
// LITERAL -> LDS offsets fold to immediates; 2-step scheduling window.
__global__ __launch_bounds__(512, 2)
void lstm_k20(const float* __restrict__ x,
              const float* __restrict__ Wih,
              const float* __restrict__ Whh,
              const float* __restrict__ bih,
              const float* __restrict__ bhh,
              unsigned short* __restrict__ sp)
{
    __shared__ LdsT lds;
    const int tid  = threadIdx.x;
    const int lane = tid & 63;
    const int wave = tid >> 6;
    const int ci   = wave >> 1;
    const int gh   = wave & 1;
    const int l16  = lane & 15;
    const int kg   = lane >> 4;
    const int bid  = blockIdx.x;
    const int xcd  = bid & 7, v = bid >> 3;        // v 0..63
    const int cg   = xcd * 32 + (v & 31);           // 0..255, XCD-contiguous groups
    const int bs   = v >> 5;                        // 0..1
    const int cellbase = cg * 4;
    const int cell = cellbase + ci;
    const int gb0  = bs * 16;

    // ---- W fragments (int4), split hi/lo via cvt_pk, pre-scaled by log2e ----
    int4 wihh[4], wihl[4], whhh[4], whhl[4];
    float biasr[4];
#pragma unroll
    for (int q = 0; q < 4; ++q) {
        const int g = q * 32 + gh * 16 + l16;
        const float* wp = Wih + (size_t)cell * 4096 + g * 32 + kg * 8;
        const float* hp = Whh + (size_t)cell * 4096 + g * 32 + kg * 8;
        float wv[8], hv[8];
#pragma unroll
        for (int j = 0; j < 8; ++j) { wv[j] = wp[j] * SCALE; hv[j] = hp[j] * SCALE; }
        unsigned a0 = cvt_pk(wv[0], wv[1]), a1 = cvt_pk(wv[2], wv[3]);
        unsigned a2 = cvt_pk(wv[4], wv[5]), a3 = cvt_pk(wv[6], wv[7]);
        wihh[q] = int4{(int)a0, (int)a1, (int)a2, (int)a3};
        wihl[q] = int4{(int)cvt_pk(wv[0] - lo16f(a0), wv[1] - hi16f(a0)),
                       (int)cvt_pk(wv[2] - lo16f(a1), wv[3] - hi16f(a1)),
                       (int)cvt_pk(wv[4] - lo16f(a2), wv[5] - hi16f(a2)),
                       (int)cvt_pk(wv[6] - lo16f(a3), wv[7] - hi16f(a3))};
        unsigned b0 = cvt_pk(hv[0], hv[1]), b1 = cvt_pk(hv[2], hv[3]);
        unsigned b2 = cvt_pk(hv[4], hv[5]), b3 = cvt_pk(hv[6], hv[7]);
        whhh[q] = int4{(int)b0, (int)b1, (int)b2, (int)b3};
        whhl[q] = int4{(int)cvt_pk(hv[0] - lo16f(b0), hv[1] - hi16f(b0)),
                       (int)cvt_pk(hv[2] - lo16f(b1), hv[3] - hi16f(b1)),
                       (int)cvt_pk(hv[4] - lo16f(b2), hv[5] - hi16f(b2)),
                       (int)cvt_pk(hv[6] - lo16f(b3), hv[7] - hi16f(b3))};
        biasr[q] = (bih[cell * 128 + g] + bhh[cell * 128 + g]) * SCALE;
    }

    // ---- x staging: thread -> (b = tid>>5, d = tid&31); float4 = 4 cells ----
    const int sb = tid >> 5;
    const int sd = tid & 31;
    const float* xg0 = x + (size_t)(gb0 + sb) * TDC + (size_t)sd * Cn + cellbase;
    const float* xcur = xg0 + DC;

    // ---- sp store map (waves 0..3): lane -> (cl = lane&3, bq = lane>>2), kg2 = wave ----
    const int cl = lane & 3, bq = lane >> 2;
    unsigned short* spq = sp + ((size_t)(gb0 + bq) * 96 + wave) * (PPXN * 8)
                             + (size_t)(cellbase + cl) * 8;

    float hD[4] = {}, cst[4] = {};
    float4 gx = *(const float4*)xg0;

#define LSTM_STEP(BUFI, TT)                                                          \
    {                                                                                \
        /* stage x: 4 cells bf16-hi */                                               \
        {                                                                            \
            unsigned u01 = cvt_pk(gx.x, gx.y), u23 = cvt_pk(gx.z, gx.w);             \
            lds.Xh[BUFI][0][sb][sd] = (unsigned short)u01;                           \
            lds.Xh[BUFI][1][sb][sd] = (unsigned short)(u01 >> 16);                   \
            lds.Xh[BUFI][2][sb][sd] = (unsigned short)u23;                           \
            lds.Xh[BUFI][3][sb][sd] = (unsigned short)(u23 >> 16);                   \
        }                                                                            \
        _Pragma("unroll")                                                            \
        for (int r = 0; r < 4; ++r)                                                  \
            lds.Hf[BUFI][ci * HSTR + (kg * 4 + r) * 36 + gh * 16 + l16] = hD[r];     \
        if ((TT) < Tn - 1) { gx = *(const float4*)xcur; xcur += DC; }                \
        lds_barrier();                                                               \
        int4 xfh = *(const int4*)&lds.Xh[BUFI][ci][l16][kg * 8];                     \
        const float* hp_ = &lds.Hf[BUFI][ci * HSTR + l16 * 36 + kg * 8];             \
        float4 ha = *(const float4*)hp_;                                             \
        float4 hb = *(const float4*)(hp_ + 4);                                       \
        unsigned p0 = cvt_pk(ha.x, ha.y), p1 = cvt_pk(ha.z, ha.w);                   \
        unsigned p2 = cvt_pk(hb.x, hb.y), p3 = cvt_pk(hb.z, hb.w);                   \
        int4 hfh = int4{(int)p0, (int)p1, (int)p2, (int)p3};                         \
        int4 hfl = int4{(int)cvt_pk(ha.x - lo16f(p0), ha.y - hi16f(p0)),             \
                        (int)cvt_pk(ha.z - lo16f(p1), ha.w - hi16f(p1)),             \
                        (int)cvt_pk(hb.x - lo16f(p2), hb.y - hi16f(p2)),             \
                        (int)cvt_pk(hb.z - lo16f(p3), hb.w - hi16f(p3))};            \
        if (wave < 4 && (TT) > 0) {                                                  \
            const float* hq_ = &lds.Hf[BUFI][cl * HSTR + bq * 36 + wave * 8];        \
            float4 e0 = *(const float4*)hq_;                                         \
            float4 e1 = *(const float4*)(hq_ + 4);                                   \
            int4 sv = {(int)cvt_pk(e0.x, e0.y), (int)cvt_pk(e0.z, e0.w),             \
                       (int)cvt_pk(e1.x, e1.y), (int)cvt_pk(e1.z, e1.w)};            \
            *(int4*)(spq + (size_t)((TT) - 1) * (4 * PPXN * 8)) = sv;                \
        }                                                                            \
        f32x4 acc[4];                                                                \
        _Pragma("unroll")                                                            \
        for (int q = 0; q < 4; ++q) {                                                \
            f32x4 a = {biasr[q], biasr[q], biasr[q], biasr[q]};                      \
            a = __builtin_amdgcn_mfma_f32_16x16x32_bf16(bc(xfh), bc(wihh[q]), a, 0, 0, 0); \
            a = __builtin_amdgcn_mfma_f32_16x16x32_bf16(bc(xfh), bc(wihl[q]), a, 0, 0, 0); \
            a = __builtin_amdgcn_mfma_f32_16x16x32_bf16(bc(hfh), bc(whhh[q]), a, 0, 0, 0); \
            a = __builtin_amdgcn_mfma_f32_16x16x32_bf16(bc(hfl), bc(whhh[q]), a, 0, 0, 0); \
            a = __builtin_amdgcn_mfma_f32_16x16x32_bf16(bc(hfh), bc(whhl[q]), a, 0, 0, 0); \
            acc[q] = a;                                                              \
        }                                                                            \
        _Pragma("unroll")                                                            \
        for (int r = 0; r < 4; ++r) {                                                \
            float gi = acc[0][r], gf = acc[1][r];                                    \
            float gg = acc[2][r], go = acc[3][r];                                    \
            float ig = rcp_(1.f + exp2_(-gi));                                       \
            float fg = rcp_(1.f + exp2_(-gf));                                       \
            float gt = 1.f - 2.f * rcp_(1.f + exp2_(gg + gg));                       \
            float og = rcp_(1.f + exp2_(-go));                                       \
            float c  = fg * cst[r] + ig * gt;                                        \
            cst[r] = c;                                                              \
            float tc = 1.f - 2.f * rcp_(1.f + exp2_((2.f * SCALE) * c));             \
            hD[r] = og * tc;                                                         \
        }                                                                            \
    }

    for (int t = 0; t < Tn; t += 2) {
        LSTM_STEP(0, t)
        LSTM_STEP(1, t + 1)
    }
#undef LSTM_STEP

    // ---- epilogue: flush h(Tn-1) ----
#pragma unroll
    for (int r = 0; r < 4; ++r)
        lds.Hf[0][ci * HSTR + (kg * 4 + r) * 36 + gh * 16 + l16] = hD[r];
    lds_barrier();
    if (wave < 4) {
        const float* hq = &lds.Hf[0][cl * HSTR + bq * 36 + wave * 8];
        float4 e0 = *(const float4*)hq;
        float4 e1 = *(const float4*)(hq + 4);
        int4 sv = {(int)cvt_pk(e0.x, e0.y), (int)cvt_pk(e0.z, e0.w),
                   (int)cvt_pk(e1.x, e1.y), (int)cvt_pk(e1.z, e1.w)};
        *(int4*)(spq + (size_t)(Tn - 1) * (4 * PPXN * 8)) = sv;
    }
}

// ---- conv: 768 blocks (b,t) x 512 thr; LDS-staged 34x34x8 bf16 tile with
//      in-LDS zero halo; predication-free inner loop; weights broadcast from LDS.
__global__ __launch_bounds__(512, 4)
void conv_k18(const unsigned short* __restrict__ sp,
              const float* __restrict__ cw,
              const float* __restrict__ cb,
              float* __restrict__ out)
{
    __shared__ unsigned short tile[34 * 34 * 8];   // 36992 B
    __shared__ float wlds[9][32];
    const int tid = threadIdx.x;
    const int img = blockIdx.x;
    if (tid < 288) wlds[tid >> 5][tid & 31] = cw[(tid & 31) * 9 + (tid >> 5)];
    if (tid < 132) {
        int r = tid, m, n;
        if (r < 34)       { m = 0;      n = r; }
        else if (r < 68)  { m = 33;     n = r - 34; }
        else if (r < 100) { m = r - 67; n = 0; }
        else              { m = r - 99; n = 33; }
        *(int4*)&tile[(m * 34 + n) * 8] = int4{0, 0, 0, 0};
    }
    const int m0 = tid >> 5, n0 = tid & 31;
    const float bias = cb[0];
    float acc[2] = {bias, bias};

#pragma unroll
    for (int hc = 0; hc < 4; ++hc) {
        const unsigned short* plane = sp + (size_t)(img * 4 + hc) * (PPXN * 8);
        int4 v0 = *(const int4*)(plane + (size_t)tid * 8);
        int4 v1 = *(const int4*)(plane + (size_t)(tid + 512) * 8);
        lds_barrier();                    // prior compute done / halo visible
        *(int4*)&tile[((m0 + 1) * 34 + n0 + 1) * 8] = v0;
        *(int4*)&tile[((m0 + 17) * 34 + n0 + 1) * 8] = v1;
        lds_barrier();

#pragma unroll
        for (int pk = 0; pk < 2; ++pk) {
            const int m = m0 + pk * 16, n = n0;
            float a = acc[pk];
#pragma unroll
            for (int dm = -1; dm <= 1; ++dm)
#pragma unroll
                for (int dn = -1; dn <= 1; ++dn) {
                    const int tap = (dm + 1) * 3 + (dn + 1);
                    int4 v = *(const int4*)&tile[((m + 1 + dm) * 34 + (n + 1 + dn)) * 8];
                    float4 w0 = *(const float4*)&wlds[tap][hc * 8];
                    float4 w1 = *(const float4*)&wlds[tap][hc * 8 + 4];
                    a = fmaf(lo16f((unsigned)v.x), w0.x, a);
                    a = fmaf(hi16f((unsigned)v.x), w0.y, a);
                    a = fmaf(lo16f((unsigned)v.y), w0.z, a);
                    a = fmaf(hi16f((unsigned)v.y), w0.w, a);
                    a = fmaf(lo16f((unsigned)v.z), w1.x, a);
                    a = fmaf(hi16f((unsigned)v.z), w1.y, a);
                    a = fmaf(lo16f((unsigned)v.w), w1.z, a);
                    a = fmaf(hi16f((unsigned)v.w), w1.w, a);
                }
            acc[pk] = a;
        }
    }
#pragma unroll
    for (int pk = 0; pk < 2; ++pk)
        out[(size_t)img * 1024 + tid + pk * 512] = rcp_(1.f + exp2_(-SCALE * acc[pk]));
}

extern "C" void kernel_launch(void* const* d_in, const int* in_sizes, int n_in,
                              void* d_out, int out_size, void* d_ws, size_t ws_size,
                              hipStream_t stream) {
    const float* x   = (const float*)d_in[0];
    const float* Wih = (const float*)d_in[1];
    const float* Whh = (const float*)d_in[2];
    const float* bih = (const float*)d_in[3];
    const float* bhh = (const float*)d_in[4];
    const float* cw  = (const float*)d_in[5];
    const float* cb  = (const float*)d_in[6];
    float* out = (float*)d_out;
    unsigned short* sp = (unsigned short*)d_ws;  // bf16 (B,T, chunk4, 32,32, 8ch), 49.2 MB

    lstm_k20<<<512, 512, 0, stream>>>(x, Wih, Whh, bih, bhh, sp);
    conv_k18<<<Bn * Tn, 512, 0, stream>>>(sp, cw, cb, out);
}